// Round 2
// 421.342 us; speedup vs baseline: 1.0361x; 1.0361x over previous
//
#include <hip/hip_runtime.h>
#include <math.h>

// Sparsemax over rows of a (16384 x 4096) float32 matrix.
//
// Bound: tau >= max(x) - 1  (z1 - tau <= sum(z_i - tau)_+ = 1), so the
// support lies in {x : x > max - 1} (~22 elems for N(0,1) rows of 4096).
// Candidates are gathered to LDS; then EVERY wave redundantly solves tau
// exactly in one pass via the rank formula: for candidate y_i,
//   C_i = #{j : y_j >= y_i},  S_i = sum{y_j : y_j >= y_i}
//   support size k = max C_i over lanes with 1 + C_i*y_i > S_i
//   tau = (S_i - 1)/C_i at that lane      (identical to the reference's
//   sorted cumsum formula for distinct values; ties are measure-zero)
// No iteration, no dependent shuffle chains, 2 barriers total.
//
// This revision: non-temporal load/store via clang ext_vector_type float4
// (HIP_vector_type is rejected by the builtin) + __launch_bounds__(256, 8)
// to guarantee VGPR <= 64 -> 8 waves/SIMD -> max TLP to hide the per-block
// serial tau-solve phase.

constexpr int N_COLS = 4096;
constexpr int BLOCK = 256;
constexpr int PER_THREAD = N_COLS / BLOCK;  // 16
constexpr int WAVES = BLOCK / 64;           // 4
constexpr int CAP = 64;                     // candidate capacity (1 wave)

typedef float vfloat4 __attribute__((ext_vector_type(4)));

__global__ __launch_bounds__(BLOCK, 8) void sparsemax_kernel(
    const float* __restrict__ x, float* __restrict__ out) {
  const int row = blockIdx.x;
  const vfloat4* x4 = (const vfloat4*)(x + (size_t)row * N_COLS);
  vfloat4* o4 = (vfloat4*)(out + (size_t)row * N_COLS);
  const int t = threadIdx.x;
  const int wave = t >> 6;
  const int lane = t & 63;

  // ---- load row into registers, coalesced float4, non-temporal ----
  float v[PER_THREAD];
#pragma unroll
  for (int k = 0; k < PER_THREAD / 4; ++k) {
    vfloat4 f = __builtin_nontemporal_load(&x4[t + k * BLOCK]);
    v[4 * k + 0] = f.x;
    v[4 * k + 1] = f.y;
    v[4 * k + 2] = f.z;
    v[4 * k + 3] = f.w;
  }

  __shared__ float s_red[WAVES];
  __shared__ float s_cand[CAP];
  __shared__ int s_n;

  // ---- row max ----
  float m = v[0];
#pragma unroll
  for (int k = 1; k < PER_THREAD; ++k) m = fmaxf(m, v[k]);
#pragma unroll
  for (int off = 32; off >= 1; off >>= 1) m = fmaxf(m, __shfl_xor(m, off, 64));
  if (lane == 0) s_red[wave] = m;
  if (t == 0) s_n = 0;
  __syncthreads();  // barrier 1
  m = fmaxf(fmaxf(s_red[0], s_red[1]), fmaxf(s_red[2], s_red[3]));

  // ---- gather candidates x > m-1 into LDS (stored shifted: y = x - m) ----
  const float thresh = m - 1.0f;
#pragma unroll
  for (int k = 0; k < PER_THREAD; ++k) {
    if (v[k] > thresh) {
      int idx = atomicAdd(&s_n, 1);
      if (idx < CAP) s_cand[idx] = v[k] - m;
    }
  }
  __syncthreads();  // barrier 2
  const int cnt = s_n;  // uniform across block

  float tau;  // in shifted space
  if (cnt <= CAP) {
    // ---- every wave solves redundantly: exact one-pass rank formula ----
    const bool in = lane < cnt;
    float y = in ? s_cand[lane] : 1.0f;  // sentinel never read via shfl(j<cnt)
    float S = 0.0f, C = 0.0f;
    for (int j = 0; j < cnt; ++j) {  // uniform trip count; shfl j is uniform
      float yj = __shfl(y, j, 64);   // lowers to readlane broadcast
      if (yj >= y) {
        S += yj;
        C += 1.0f;
      }
    }
    bool ok = in && (1.0f + C * y > S);
    float bc = ok ? C : 0.0f;
    float bt = ok ? (S - 1.0f) / C : 0.0f;
#pragma unroll
    for (int off = 32; off >= 1; off >>= 1) {
      float oc = __shfl_xor(bc, off, 64);
      float ot = __shfl_xor(bt, off, 64);
      if (oc > bc) {
        bc = oc;
        bt = ot;
      }
    }
    tau = bt;  // uniform across wave (k=max C is unique for distinct values)
  } else {
    // ---- fallback (statistically never): block-wide Michelot ----
    __shared__ float s_sum[WAVES];
    __shared__ float s_cnt[WAVES];
    __shared__ float s_b[2];
    unsigned act = (1u << PER_THREAD) - 1;
    float tb = 0.0f;
    int prev_cnt = -1;
    for (int it = 0; it < 64; ++it) {
      float s = 0.0f, c = 0.0f;
#pragma unroll
      for (int k = 0; k < PER_THREAD; ++k) {
        if ((act >> k) & 1u) {
          s += v[k] - m;
          c += 1.0f;
        }
      }
#pragma unroll
      for (int off = 32; off >= 1; off >>= 1) {
        s += __shfl_down(s, off, 64);
        c += __shfl_down(c, off, 64);
      }
      if (lane == 0) {
        s_sum[wave] = s;
        s_cnt[wave] = c;
      }
      __syncthreads();
      if (t == 0) {
        float ss = 0.0f, cc = 0.0f;
        for (int w = 0; w < WAVES; ++w) {
          ss += s_sum[w];
          cc += s_cnt[w];
        }
        s_b[0] = (ss - 1.0f) / cc;
        s_b[1] = cc;
      }
      __syncthreads();
      tb = s_b[0];
      int c_now = (int)s_b[1];
      __syncthreads();
      if (c_now == prev_cnt) break;
      prev_cnt = c_now;
#pragma unroll
      for (int k = 0; k < PER_THREAD; ++k) {
        if (((act >> k) & 1u) && (v[k] - m) <= tb) act &= ~(1u << k);
      }
    }
    tau = tb;
  }

  // ---- write out = max(x - (m + tau), 0), coalesced float4, non-temporal ----
  const float T = m + tau;
#pragma unroll
  for (int k = 0; k < PER_THREAD / 4; ++k) {
    vfloat4 f;
    f.x = fmaxf(v[4 * k + 0] - T, 0.0f);
    f.y = fmaxf(v[4 * k + 1] - T, 0.0f);
    f.z = fmaxf(v[4 * k + 2] - T, 0.0f);
    f.w = fmaxf(v[4 * k + 3] - T, 0.0f);
    __builtin_nontemporal_store(f, &o4[t + k * BLOCK]);
  }
}

extern "C" void kernel_launch(void* const* d_in, const int* in_sizes, int n_in,
                              void* d_out, int out_size, void* d_ws,
                              size_t ws_size, hipStream_t stream) {
  const float* x = (const float*)d_in[0];
  float* out = (float*)d_out;
  const int rows = in_sizes[0] / N_COLS;  // 16384
  sparsemax_kernel<<<rows, BLOCK, 0, stream>>>(x, out);
}